// Round 1
// baseline (1695.892 us; speedup 1.0000x reference)
//
#include <hip/hip_runtime.h>
#include <hip/hip_bf16.h>
#include <math.h>

// RelPositionMultiheadAttention (Transformer-XL style), fp32 baseline.
// L=2048, N=4, E=256, H=4, D=64.
// Pipeline:
//   1) qkv  = x @ in_proj_w.T + b          (8192x768)
//   2) p    = pos_emb @ pos_w.T            (4095x256)
//   3) fused flash-style attention with rel-shift folded into p indexing
//   4) out  = attn @ out_proj_w.T + b      (8192x256)

namespace {
constexpr int L_SEQ  = 2048;
constexpr int NB     = 4;
constexpr int EMB    = 256;
constexpr int NH     = 4;
constexpr int HD     = 64;
constexpr int E3     = 768;
constexpr int M_ROWS = L_SEQ * NB;     // 8192
constexpr int P_ROWS = 2 * L_SEQ - 1;  // 4095
}

// ---------------------------------------------------------------------------
// Generic C = A * B^T + bias.  A:(M,K) rm, B:(Nc,K) rm, C:(M,Nc) rm.
// 64x64 tile, BK=16, 256 threads, 4x4 per thread.
// ---------------------------------------------------------------------------
__global__ __launch_bounds__(256) void gemm_abt(const float* __restrict__ A,
                                                const float* __restrict__ B,
                                                const float* __restrict__ bias,
                                                float* __restrict__ C,
                                                int M, int Nc, int K) {
    __shared__ float As[16][64];   // [k][m]
    __shared__ float Bs[16][64];   // [k][n]
    const int t  = threadIdx.x;
    const int tx = t & 15, ty = t >> 4;
    const int n0 = blockIdx.x * 64;
    const int m0 = blockIdx.y * 64;
    const int r  = t >> 2;        // 0..63
    const int c  = (t & 3) * 4;   // 0,4,8,12

    float acc[4][4] = {};

    for (int k0 = 0; k0 < K; k0 += 16) {
        {
            int m = m0 + r;
            float4 av = make_float4(0.f, 0.f, 0.f, 0.f);
            if (m < M) av = *(const float4*)&A[(size_t)m * K + k0 + c];
            As[c + 0][r] = av.x; As[c + 1][r] = av.y;
            As[c + 2][r] = av.z; As[c + 3][r] = av.w;
            float4 bv = *(const float4*)&B[(size_t)(n0 + r) * K + k0 + c];
            Bs[c + 0][r] = bv.x; Bs[c + 1][r] = bv.y;
            Bs[c + 2][r] = bv.z; Bs[c + 3][r] = bv.w;
        }
        __syncthreads();
        #pragma unroll
        for (int kk = 0; kk < 16; ++kk) {
            float4 a4 = *(const float4*)&As[kk][ty * 4];
            float4 b4 = *(const float4*)&Bs[kk][tx * 4];
            float ar[4] = {a4.x, a4.y, a4.z, a4.w};
            float br[4] = {b4.x, b4.y, b4.z, b4.w};
            #pragma unroll
            for (int a = 0; a < 4; ++a)
                #pragma unroll
                for (int b = 0; b < 4; ++b)
                    acc[a][b] += ar[a] * br[b];
        }
        __syncthreads();
    }

    #pragma unroll
    for (int a = 0; a < 4; ++a) {
        int m = m0 + ty * 4 + a;
        if (m >= M) continue;
        float4 o;
        o.x = acc[a][0] + (bias ? bias[n0 + tx * 4 + 0] : 0.f);
        o.y = acc[a][1] + (bias ? bias[n0 + tx * 4 + 1] : 0.f);
        o.z = acc[a][2] + (bias ? bias[n0 + tx * 4 + 2] : 0.f);
        o.w = acc[a][3] + (bias ? bias[n0 + tx * 4 + 3] : 0.f);
        *(float4*)&C[(size_t)m * Nc + n0 + tx * 4] = o;
    }
}

// ---------------------------------------------------------------------------
// Fused rel-pos attention.
//  grid = (L/64, NB*NH), block = 256.
//  Each block: one (b,h), one 64-row Q tile. Loops over 32 K-tiles of 64.
//  S[i][j] = (q[i]*sc + u_h) . k[j]  +  (q[i]*sc + v_h) . p[L-1-i+j]
//  Row i is owned by the 4-lane quad {4*di .. 4*di+3}; each lane holds 16
//  score columns (score phase) and 16 output dims (PV phase).
// LDS layouts (exactly 64 KiB total):
//  k_s[d][j]  (transposed) -> score reads conflict-light
//  p_s[d][r]  (transposed) -> per-lane r spreads across banks
//  v_s[j][d]  (natural)    -> PV float4 reads, 2-way max
// ---------------------------------------------------------------------------
__global__ __launch_bounds__(256) void attn_kernel(const float* __restrict__ qkv,
                                                   const float* __restrict__ p,
                                                   const float* __restrict__ u_bias,
                                                   const float* __restrict__ v_bias,
                                                   float* __restrict__ attn_out) {
    __shared__ float k_s[64 * 64];    // [d][j]   16 KiB
    __shared__ float v_s[64 * 64];    // [j][d]   16 KiB
    __shared__ float p_s[64 * 128];   // [d][r]   32 KiB

    const int t    = threadIdx.x;
    const int quad = t & 3;
    const int di   = t >> 2;            // 0..63 (row within tile)
    const int i0   = blockIdx.x * 64;
    const int bh   = blockIdx.y;
    const int b    = bh >> 2;           // / NH
    const int h    = bh & 3;            // % NH
    const int i    = i0 + di;
    const float scaling = 0.125f;       // 1/sqrt(D)

    // q row fragment (this lane's 16 dims), pre-biased both ways
    float qu[16], qv[16];
    {
        const float* qrow = &qkv[((size_t)i * NB + b) * E3 + h * HD + quad * 16];
        #pragma unroll
        for (int q4 = 0; q4 < 4; ++q4) {
            float4 x4  = *(const float4*)&qrow[q4 * 4];
            float4 u4  = *(const float4*)&u_bias[h * HD + quad * 16 + q4 * 4];
            float4 vb4 = *(const float4*)&v_bias[h * HD + quad * 16 + q4 * 4];
            qu[q4 * 4 + 0] = x4.x * scaling + u4.x;
            qu[q4 * 4 + 1] = x4.y * scaling + u4.y;
            qu[q4 * 4 + 2] = x4.z * scaling + u4.z;
            qu[q4 * 4 + 3] = x4.w * scaling + u4.w;
            qv[q4 * 4 + 0] = x4.x * scaling + vb4.x;
            qv[q4 * 4 + 1] = x4.y * scaling + vb4.y;
            qv[q4 * 4 + 2] = x4.z * scaling + vb4.z;
            qv[q4 * 4 + 3] = x4.w * scaling + vb4.w;
        }
    }

    float m_run = -INFINITY, l_run = 0.f;
    float acc[16];
    #pragma unroll
    for (int z = 0; z < 16; ++z) acc[z] = 0.f;

    for (int kt = 0; kt < 32; ++kt) {
        const int j0 = kt * 64;

        // ---- stage K and V tiles ----
        {
            const int j  = t >> 2;          // 0..63
            const int d4 = (t & 3) * 16;
            const float* krow = &qkv[((size_t)(j0 + j) * NB + b) * E3 + EMB + h * HD + d4];
            const float* vrow = &qkv[((size_t)(j0 + j) * NB + b) * E3 + 2 * EMB + h * HD + d4];
            #pragma unroll
            for (int q4 = 0; q4 < 4; ++q4) {
                float4 kv = *(const float4*)&krow[q4 * 4];
                k_s[(d4 + q4 * 4 + 0) * 64 + j] = kv.x;
                k_s[(d4 + q4 * 4 + 1) * 64 + j] = kv.y;
                k_s[(d4 + q4 * 4 + 2) * 64 + j] = kv.z;
                k_s[(d4 + q4 * 4 + 3) * 64 + j] = kv.w;
                *(float4*)&v_s[j * 64 + d4 + q4 * 4] = *(const float4*)&vrow[q4 * 4];
            }
        }
        // ---- stage P tile: rows n = base..base+126, base = L-1-(i0+63)+j0 ----
        {
            const int r = t >> 1;           // 0..127 (127 used)
            const int c32 = (t & 1) * 32;
            if (r < 127) {
                const int n = (L_SEQ - 1 - 63) - i0 + j0 + r;   // 1984 - i0 + j0 + r
                const float* prow = &p[(size_t)n * EMB + h * HD + c32];
                #pragma unroll
                for (int q4 = 0; q4 < 8; ++q4) {
                    float4 pv = *(const float4*)&prow[q4 * 4];
                    p_s[(c32 + q4 * 4 + 0) * 128 + r] = pv.x;
                    p_s[(c32 + q4 * 4 + 1) * 128 + r] = pv.y;
                    p_s[(c32 + q4 * 4 + 2) * 128 + r] = pv.z;
                    p_s[(c32 + q4 * 4 + 3) * 128 + r] = pv.w;
                }
            }
        }
        __syncthreads();

        // ---- scores: this lane's 16 columns j = quad*16 + jj ----
        float sreg[16];
        #pragma unroll
        for (int jj = 0; jj < 16; ++jj) sreg[jj] = 0.f;
        const int rbase = 63 - di + quad * 16;   // r = rbase + jj in [0,126]
        #pragma unroll
        for (int d = 0; d < 64; ++d) {
            float qud = __shfl(qu[d & 15], d >> 4, 4);
            float qvd = __shfl(qv[d & 15], d >> 4, 4);
            const float* krow = &k_s[d * 64 + quad * 16];
            const float* prow = &p_s[d * 128 + rbase];
            #pragma unroll
            for (int q4 = 0; q4 < 4; ++q4) {
                float4 k4 = *(const float4*)&krow[q4 * 4];
                sreg[q4 * 4 + 0] += qud * k4.x + qvd * prow[q4 * 4 + 0];
                sreg[q4 * 4 + 1] += qud * k4.y + qvd * prow[q4 * 4 + 1];
                sreg[q4 * 4 + 2] += qud * k4.z + qvd * prow[q4 * 4 + 2];
                sreg[q4 * 4 + 3] += qud * k4.w + qvd * prow[q4 * 4 + 3];
            }
        }

        // ---- online softmax (quad owns the row) ----
        float mx = sreg[0];
        #pragma unroll
        for (int jj = 1; jj < 16; ++jj) mx = fmaxf(mx, sreg[jj]);
        mx = fmaxf(mx, __shfl_xor(mx, 1, 4));
        mx = fmaxf(mx, __shfl_xor(mx, 2, 4));
        float m_new = fmaxf(m_run, mx);
        float corr  = __expf(m_run - m_new);   // 0 on first tile (-inf - finite)
        float pexp[16];
        float psum = 0.f;
        #pragma unroll
        for (int jj = 0; jj < 16; ++jj) {
            pexp[jj] = __expf(sreg[jj] - m_new);
            psum += pexp[jj];
        }
        psum += __shfl_xor(psum, 1, 4);
        psum += __shfl_xor(psum, 2, 4);
        l_run = l_run * corr + psum;
        m_run = m_new;
        #pragma unroll
        for (int z = 0; z < 16; ++z) acc[z] *= corr;

        // ---- PV: acc[dd] += sum_j P[i][j] * v[j][d], d = quad*16+dd ----
        #pragma unroll
        for (int j = 0; j < 64; ++j) {
            float pij = __shfl(pexp[j & 15], j >> 4, 4);
            const float* vrow = &v_s[j * 64 + quad * 16];
            #pragma unroll
            for (int q4 = 0; q4 < 4; ++q4) {
                float4 v4 = *(const float4*)&vrow[q4 * 4];
                acc[q4 * 4 + 0] += pij * v4.x;
                acc[q4 * 4 + 1] += pij * v4.y;
                acc[q4 * 4 + 2] += pij * v4.z;
                acc[q4 * 4 + 3] += pij * v4.w;
            }
        }
        __syncthreads();
    }

    // ---- epilogue: normalize, write (L,N,E) layout ----
    const float inv_l = 1.f / l_run;
    float* orow = &attn_out[((size_t)i * NB + b) * EMB + h * HD + quad * 16];
    #pragma unroll
    for (int q4 = 0; q4 < 4; ++q4) {
        float4 o;
        o.x = acc[q4 * 4 + 0] * inv_l;
        o.y = acc[q4 * 4 + 1] * inv_l;
        o.z = acc[q4 * 4 + 2] * inv_l;
        o.w = acc[q4 * 4 + 3] * inv_l;
        *(float4*)&orow[q4 * 4] = o;
    }
}

// ---------------------------------------------------------------------------
extern "C" void kernel_launch(void* const* d_in, const int* in_sizes, int n_in,
                              void* d_out, int out_size, void* d_ws, size_t ws_size,
                              hipStream_t stream) {
    const float* x        = (const float*)d_in[0];
    const float* pos_emb  = (const float*)d_in[1];
    const float* in_w     = (const float*)d_in[2];
    const float* in_b     = (const float*)d_in[3];
    const float* pos_w    = (const float*)d_in[4];
    const float* u_bias   = (const float*)d_in[5];
    const float* v_bias   = (const float*)d_in[6];
    const float* out_w    = (const float*)d_in[7];
    const float* out_b    = (const float*)d_in[8];
    float* out = (float*)d_out;

    // workspace: qkv (8192x768) | p (4095x256) | attn (8192x256)  ~= 36 MiB
    float* qkv  = (float*)d_ws;
    float* pbuf = qkv + (size_t)M_ROWS * E3;
    float* attn = pbuf + (size_t)P_ROWS * EMB;

    gemm_abt<<<dim3(E3 / 64, M_ROWS / 64), 256, 0, stream>>>(
        x, in_w, in_b, qkv, M_ROWS, E3, EMB);
    gemm_abt<<<dim3(EMB / 64, (P_ROWS + 63) / 64), 256, 0, stream>>>(
        pos_emb, pos_w, nullptr, pbuf, P_ROWS, EMB, EMB);
    attn_kernel<<<dim3(L_SEQ / 64, NB * NH), 256, 0, stream>>>(
        qkv, pbuf, u_bias, v_bias, attn);
    gemm_abt<<<dim3(EMB / 64, M_ROWS / 64), 256, 0, stream>>>(
        attn, out_w, out_b, out, M_ROWS, EMB, EMB);
}

// Round 2
// 244.593 us; speedup vs baseline: 6.9335x; 6.9335x over previous
//
#include <hip/hip_runtime.h>
#include <math.h>
#include <stdint.h>

// RelPositionMultiheadAttention (Transformer-XL style).
// L=2048, N=4, E=256, H=4, D=64.
//   1) qkv  = x @ in_proj_w.T + b      (fp32 gemm, 8192x768)
//   2) pbuf = pos_emb @ pos_w.T        (fp32 gemm, 4095x256)
//   3) prep: fp32 -> fp16 buffers  qu=(q*s+u), qv=(q*s+v), K, V^T, P(per-head)
//   4) fused flash attention, fp16 MFMA (16x16x32), rel-shift via banded BD^T
//   5) out  = attn @ out_proj_w.T + b  (fp32 gemm)

typedef __attribute__((ext_vector_type(8))) _Float16 half8;
typedef __attribute__((ext_vector_type(4))) float f32x4;
typedef unsigned short u16;
typedef unsigned int u32;

namespace {
constexpr int L_SEQ  = 2048;
constexpr int NB     = 4;
constexpr int EMB    = 256;
constexpr int NH     = 4;
constexpr int HD     = 64;
constexpr int E3     = 768;
constexpr int M_ROWS = L_SEQ * NB;     // 8192
constexpr int P_ROWS = 2 * L_SEQ - 1;  // 4095
}

__device__ __forceinline__ u16 f2h(float x) {
    _Float16 h = (_Float16)x;
    return __builtin_bit_cast(u16, h);
}

// ---------------------------------------------------------------------------
// Generic C = A * B^T + bias (fp32).  A:(M,K) rm, B:(Nc,K) rm, C:(M,Nc) rm.
// ---------------------------------------------------------------------------
__global__ __launch_bounds__(256) void gemm_abt(const float* __restrict__ A,
                                                const float* __restrict__ B,
                                                const float* __restrict__ bias,
                                                float* __restrict__ C,
                                                int M, int Nc, int K) {
    __shared__ float As[16][64];
    __shared__ float Bs[16][64];
    const int t  = threadIdx.x;
    const int tx = t & 15, ty = t >> 4;
    const int n0 = blockIdx.x * 64;
    const int m0 = blockIdx.y * 64;
    const int r  = t >> 2;
    const int c  = (t & 3) * 4;

    float acc[4][4] = {};

    for (int k0 = 0; k0 < K; k0 += 16) {
        {
            int m = m0 + r;
            float4 av = make_float4(0.f, 0.f, 0.f, 0.f);
            if (m < M) av = *(const float4*)&A[(size_t)m * K + k0 + c];
            As[c + 0][r] = av.x; As[c + 1][r] = av.y;
            As[c + 2][r] = av.z; As[c + 3][r] = av.w;
            float4 bv = *(const float4*)&B[(size_t)(n0 + r) * K + k0 + c];
            Bs[c + 0][r] = bv.x; Bs[c + 1][r] = bv.y;
            Bs[c + 2][r] = bv.z; Bs[c + 3][r] = bv.w;
        }
        __syncthreads();
        #pragma unroll
        for (int kk = 0; kk < 16; ++kk) {
            float4 a4 = *(const float4*)&As[kk][ty * 4];
            float4 b4 = *(const float4*)&Bs[kk][tx * 4];
            float ar[4] = {a4.x, a4.y, a4.z, a4.w};
            float br[4] = {b4.x, b4.y, b4.z, b4.w};
            #pragma unroll
            for (int a = 0; a < 4; ++a)
                #pragma unroll
                for (int bb = 0; bb < 4; ++bb)
                    acc[a][bb] += ar[a] * br[bb];
        }
        __syncthreads();
    }

    #pragma unroll
    for (int a = 0; a < 4; ++a) {
        int m = m0 + ty * 4 + a;
        if (m >= M) continue;
        float4 o;
        o.x = acc[a][0] + (bias ? bias[n0 + tx * 4 + 0] : 0.f);
        o.y = acc[a][1] + (bias ? bias[n0 + tx * 4 + 1] : 0.f);
        o.z = acc[a][2] + (bias ? bias[n0 + tx * 4 + 2] : 0.f);
        o.w = acc[a][3] + (bias ? bias[n0 + tx * 4 + 3] : 0.f);
        *(float4*)&C[(size_t)m * Nc + n0 + tx * 4] = o;
    }
}

// ---------------------------------------------------------------------------
// prep: qkv fp32 -> fp16 {qu, qv, k} [bh][i][d] and vt [bh][d][j] (transposed)
// grid (L/64, 16), block 256
// ---------------------------------------------------------------------------
__global__ __launch_bounds__(256) void prep_qkv(const float* __restrict__ qkv,
                                                const float* __restrict__ u_bias,
                                                const float* __restrict__ v_bias,
                                                u16* __restrict__ quB, u16* __restrict__ qvB,
                                                u16* __restrict__ kB,  u16* __restrict__ vtB) {
    __shared__ float vtile[64][65];
    const int t  = threadIdx.x;
    const int bh = blockIdx.y, b = bh >> 2, h = bh & 3;
    const int r0 = blockIdx.x * 64;
    const int r  = t >> 2, c16 = (t & 3) * 16;
    const int row = r0 + r;

    const float* base = &qkv[((size_t)row * NB + b) * E3 + h * HD + c16];
    const float sc = 0.125f;
    u32 qup[8], qvp[8], kp[8];
    #pragma unroll
    for (int q4 = 0; q4 < 4; ++q4) {
        float4 xq = *(const float4*)&base[q4 * 4];
        float4 xk = *(const float4*)&base[EMB + q4 * 4];
        float4 xv = *(const float4*)&base[2 * EMB + q4 * 4];
        float4 ub = *(const float4*)&u_bias[h * HD + c16 + q4 * 4];
        float4 vb = *(const float4*)&v_bias[h * HD + c16 + q4 * 4];
        qup[q4*2+0] = (u32)f2h(xq.x*sc + ub.x) | ((u32)f2h(xq.y*sc + ub.y) << 16);
        qup[q4*2+1] = (u32)f2h(xq.z*sc + ub.z) | ((u32)f2h(xq.w*sc + ub.w) << 16);
        qvp[q4*2+0] = (u32)f2h(xq.x*sc + vb.x) | ((u32)f2h(xq.y*sc + vb.y) << 16);
        qvp[q4*2+1] = (u32)f2h(xq.z*sc + vb.z) | ((u32)f2h(xq.w*sc + vb.w) << 16);
        kp[q4*2+0]  = (u32)f2h(xk.x) | ((u32)f2h(xk.y) << 16);
        kp[q4*2+1]  = (u32)f2h(xk.z) | ((u32)f2h(xk.w) << 16);
        vtile[r][c16 + q4*4 + 0] = xv.x;
        vtile[r][c16 + q4*4 + 1] = xv.y;
        vtile[r][c16 + q4*4 + 2] = xv.z;
        vtile[r][c16 + q4*4 + 3] = xv.w;
    }
    size_t o = ((size_t)bh * L_SEQ + row) * HD + c16;
    *(uint4*)&quB[o]     = make_uint4(qup[0], qup[1], qup[2], qup[3]);
    *(uint4*)&quB[o + 8] = make_uint4(qup[4], qup[5], qup[6], qup[7]);
    *(uint4*)&qvB[o]     = make_uint4(qvp[0], qvp[1], qvp[2], qvp[3]);
    *(uint4*)&qvB[o + 8] = make_uint4(qvp[4], qvp[5], qvp[6], qvp[7]);
    *(uint4*)&kB[o]      = make_uint4(kp[0], kp[1], kp[2], kp[3]);
    *(uint4*)&kB[o + 8]  = make_uint4(kp[4], kp[5], kp[6], kp[7]);

    __syncthreads();
    const int d = t >> 2, jc = (t & 3) * 16;
    u32 vv[8];
    #pragma unroll
    for (int p2 = 0; p2 < 8; ++p2)
        vv[p2] = (u32)f2h(vtile[jc + p2*2][d]) | ((u32)f2h(vtile[jc + p2*2 + 1][d]) << 16);
    size_t vo = ((size_t)bh * HD + d) * L_SEQ + r0 + jc;
    *(uint4*)&vtB[vo]     = make_uint4(vv[0], vv[1], vv[2], vv[3]);
    *(uint4*)&vtB[vo + 8] = make_uint4(vv[4], vv[5], vv[6], vv[7]);
}

// ---------------------------------------------------------------------------
// prep: pbuf fp32 (4095x256) -> fp16 pB [h][n][d]
// ---------------------------------------------------------------------------
__global__ __launch_bounds__(256) void prep_p(const float* __restrict__ pbuf,
                                              u16* __restrict__ pB) {
    const int t = threadIdx.x;
    const int n = blockIdx.x * 64 + (t >> 2);
    const int c16 = (t & 3) * 16;
    if (n >= P_ROWS) return;
    #pragma unroll
    for (int h = 0; h < NH; ++h) {
        const float* src = &pbuf[(size_t)n * EMB + h * HD + c16];
        u32 pp[8];
        #pragma unroll
        for (int q4 = 0; q4 < 4; ++q4) {
            float4 x = *(const float4*)&src[q4 * 4];
            pp[q4*2+0] = (u32)f2h(x.x) | ((u32)f2h(x.y) << 16);
            pp[q4*2+1] = (u32)f2h(x.z) | ((u32)f2h(x.w) << 16);
        }
        size_t o = ((size_t)h * P_ROWS + n) * HD + c16;
        *(uint4*)&pB[o]     = make_uint4(pp[0], pp[1], pp[2], pp[3]);
        *(uint4*)&pB[o + 8] = make_uint4(pp[4], pp[5], pp[6], pp[7]);
    }
}

// ---------------------------------------------------------------------------
// Fused rel-pos flash attention, fp16 MFMA, all-transposed layout.
// grid 512 (XCD-swizzled -> (bh, i0)), block 256 = 4 waves, 64 q-rows/block.
// Per wave: 16 q-cols (il = lane&15). S^T = mfma(K, Qu); BD^T = mfma(P, Qv)
// into banded LDS buffer; Out^T = mfma(V^T, prob). D-layout col = q-index
// everywhere -> lane-uniform softmax state.
// LDS fp16 tiles swizzled: byte_in_row ^= (row&7)<<4 (write & read).
// ---------------------------------------------------------------------------
__global__ __launch_bounds__(256, 2) void attn_mfma(
        const u16* __restrict__ quB, const u16* __restrict__ qvB,
        const u16* __restrict__ kB,  const u16* __restrict__ vtB,
        const u16* __restrict__ pB,  float* __restrict__ attn_out) {
    __shared__ __align__(16) u16   k_s[64 * 64];      // [j][d]   8 KB
    __shared__ __align__(16) u16   v_s[64 * 64];      // [d][j]   8 KB
    __shared__ __align__(16) u16   p_s[128 * 64];     // [r][d]  16 KB
    __shared__ __align__(16) float bd_s[4][16 * 84];  // per-wave [il][rr] 21 KB
    __shared__ __align__(16) u16   prob_s[4][16 * 64];// per-wave [il][j]  8 KB

    const int t    = threadIdx.x;
    const int lane = t & 63;
    const int w    = t >> 6;
    const int il   = lane & 15;
    const int g    = lane >> 4;

    // XCD-aware decode: each XCD gets 64 consecutive logical ids = 2 bh groups
    const int logical = ((blockIdx.x & 7) << 6) + (blockIdx.x >> 3);
    const int bh = logical >> 5;
    const int i0 = (logical & 31) * 64;
    const int b  = bh >> 2, h = bh & 3;

    // Q fragments, held in registers for the whole kernel (B-operand layout)
    half8 qu_f[2], qv_f[2];
    {
        const size_t qrow = ((size_t)bh * L_SEQ + i0 + w * 16 + il) * HD;
        qu_f[0] = *(const half8*)&quB[qrow + g * 8];
        qu_f[1] = *(const half8*)&quB[qrow + 32 + g * 8];
        qv_f[0] = *(const half8*)&qvB[qrow + g * 8];
        qv_f[1] = *(const half8*)&qvB[qrow + 32 + g * 8];
    }

    // tile-invariant LDS byte offsets
    const int r0w = 48 - 16 * w;
    int krd[4][2], prd[5][2], pbrd[2], pwr[4];
    #pragma unroll
    for (int x4 = 0; x4 < 4; ++x4)
        #pragma unroll
        for (int c = 0; c < 2; ++c) {
            int row = x4 * 16 + il;
            krd[x4][c] = row * 128 + ((c * 64 + g * 16) ^ ((row & 7) << 4));
        }
    #pragma unroll
    for (int rt = 0; rt < 5; ++rt)
        #pragma unroll
        for (int c = 0; c < 2; ++c) {
            int row = r0w + rt * 16 + il;
            prd[rt][c] = row * 128 + ((c * 64 + g * 16) ^ ((row & 7) << 4));
        }
    #pragma unroll
    for (int c = 0; c < 2; ++c)
        pbrd[c] = il * 128 + ((c * 64 + g * 16) ^ ((il & 7) << 4));
    #pragma unroll
    for (int jt = 0; jt < 4; ++jt)
        pwr[jt] = il * 128 + (((jt * 16 + g * 4) * 2) ^ ((il & 7) << 4));
    const int bdwr = il * 84 + g * 4;        // + rt*16
    const int bdrd = il * 83 + 15 + g * 4;   // + jt*16 + tt

    f32x4 outacc[4] = {};
    float m_run = -INFINITY, l_run = 0.f;

    for (int kt = 0; kt < 32; ++kt) {
        const int j0 = kt * 64;
        const int nbase = 1984 - i0 + j0;
        __syncthreads();
        // ---- stage K, V^T, P tiles (fp16, swizzled) ----
        {
            const int rw = t >> 3;    // 0..31
            const int a  = t & 7;
            #pragma unroll
            for (int kr = 0; kr < 2; ++kr) {
                const int j = kr * 32 + rw;
                uint4 val = *(const uint4*)&kB[((size_t)bh * L_SEQ + j0 + j) * HD + a * 8];
                *(uint4*)((char*)k_s + (j * 128 + ((a * 16) ^ ((j & 7) << 4)))) = val;
            }
            #pragma unroll
            for (int vr = 0; vr < 2; ++vr) {
                const int d = vr * 32 + rw;
                uint4 val = *(const uint4*)&vtB[((size_t)bh * HD + d) * L_SEQ + j0 + a * 8];
                *(uint4*)((char*)v_s + (d * 128 + ((a * 16) ^ ((d & 7) << 4)))) = val;
            }
            #pragma unroll
            for (int pr = 0; pr < 4; ++pr) {
                const int r = pr * 32 + rw;
                int n = nbase + r; n = n > (P_ROWS - 1) ? (P_ROWS - 1) : n;
                uint4 val = *(const uint4*)&pB[((size_t)h * P_ROWS + n) * HD + a * 8];
                *(uint4*)((char*)p_s + (r * 128 + ((a * 16) ^ ((r & 7) << 4)))) = val;
            }
        }
        __syncthreads();

        // ---- BD^T band: 5 r-tiles -> bd_s[w][il][rr] ----
        #pragma unroll
        for (int rt = 0; rt < 5; ++rt) {
            f32x4 acc = {};
            #pragma unroll
            for (int c = 0; c < 2; ++c) {
                half8 a = *(const half8*)((const char*)p_s + prd[rt][c]);
                acc = __builtin_amdgcn_mfma_f32_16x16x32_f16(a, qv_f[c], acc, 0, 0, 0);
            }
            *(f32x4*)&bd_s[w][bdwr + rt * 16] = acc;
        }

        // ---- AC (S^T) + rel-shift combine ----
        float sreg[16];
        #pragma unroll
        for (int jt = 0; jt < 4; ++jt) {
            f32x4 acc = {};
            #pragma unroll
            for (int c = 0; c < 2; ++c) {
                half8 a = *(const half8*)((const char*)k_s + krd[jt][c]);
                acc = __builtin_amdgcn_mfma_f32_16x16x32_f16(a, qu_f[c], acc, 0, 0, 0);
            }
            #pragma unroll
            for (int tt = 0; tt < 4; ++tt)
                sreg[jt * 4 + tt] = acc[tt] + bd_s[w][bdrd + jt * 16 + tt];
        }

        // ---- online softmax (q-col il; partners at lane^16, lane^32) ----
        float mx = sreg[0];
        #pragma unroll
        for (int z = 1; z < 16; ++z) mx = fmaxf(mx, sreg[z]);
        mx = fmaxf(mx, __shfl_xor(mx, 16));
        mx = fmaxf(mx, __shfl_xor(mx, 32));
        const float m_new = fmaxf(m_run, mx);
        const float corr = __expf(m_run - m_new);
        float lsum = 0.f;
        #pragma unroll
        for (int z = 0; z < 16; ++z) { sreg[z] = __expf(sreg[z] - m_new); lsum += sreg[z]; }
        lsum += __shfl_xor(lsum, 16);
        lsum += __shfl_xor(lsum, 32);
        l_run = l_run * corr + lsum;
        m_run = m_new;
        #pragma unroll
        for (int dt = 0; dt < 4; ++dt) outacc[dt] *= corr;

        // ---- pack probabilities -> prob_s[w][il][j] (fp16, swizzled) ----
        #pragma unroll
        for (int jt = 0; jt < 4; ++jt) {
            u32 lo = (u32)f2h(sreg[jt * 4 + 0]) | ((u32)f2h(sreg[jt * 4 + 1]) << 16);
            u32 hi = (u32)f2h(sreg[jt * 4 + 2]) | ((u32)f2h(sreg[jt * 4 + 3]) << 16);
            *(uint2*)((char*)&prob_s[w][0] + pwr[jt]) = make_uint2(lo, hi);
        }

        // ---- PV: Out^T += mfma(V^T, prob) ----
        half8 pfrag[2];
        #pragma unroll
        for (int c = 0; c < 2; ++c)
            pfrag[c] = *(const half8*)((const char*)&prob_s[w][0] + pbrd[c]);
        #pragma unroll
        for (int dt = 0; dt < 4; ++dt) {
            #pragma unroll
            for (int c = 0; c < 2; ++c) {
                half8 a = *(const half8*)((const char*)v_s + krd[dt][c]);
                outacc[dt] = __builtin_amdgcn_mfma_f32_16x16x32_f16(a, pfrag[c], outacc[dt], 0, 0, 0);
            }
        }
    }

    // ---- epilogue ----
    const float inv = 1.f / l_run;
    float* orow = &attn_out[((size_t)(i0 + w * 16 + il) * NB + b) * EMB + h * HD];
    #pragma unroll
    for (int dt = 0; dt < 4; ++dt) {
        float4 o = make_float4(outacc[dt][0] * inv, outacc[dt][1] * inv,
                               outacc[dt][2] * inv, outacc[dt][3] * inv);
        *(float4*)&orow[dt * 16 + g * 4] = o;
    }
}

// ---------------------------------------------------------------------------
extern "C" void kernel_launch(void* const* d_in, const int* in_sizes, int n_in,
                              void* d_out, int out_size, void* d_ws, size_t ws_size,
                              hipStream_t stream) {
    const float* x        = (const float*)d_in[0];
    const float* pos_emb  = (const float*)d_in[1];
    const float* in_w     = (const float*)d_in[2];
    const float* in_b     = (const float*)d_in[3];
    const float* pos_w    = (const float*)d_in[4];
    const float* u_bias   = (const float*)d_in[5];
    const float* v_bias   = (const float*)d_in[6];
    const float* out_w    = (const float*)d_in[7];
    const float* out_b    = (const float*)d_in[8];
    float* out = (float*)d_out;

    // workspace layout (~57 MB)
    float* qkv   = (float*)d_ws;
    float* pbuf  = qkv  + (size_t)M_ROWS * E3;
    float* attnb = pbuf + (size_t)P_ROWS * EMB;
    u16*  quB = (u16*)(attnb + (size_t)M_ROWS * EMB);
    u16*  qvB = quB + (size_t)16 * L_SEQ * HD;
    u16*  kB  = qvB + (size_t)16 * L_SEQ * HD;
    u16*  vtB = kB  + (size_t)16 * L_SEQ * HD;
    u16*  pB  = vtB + (size_t)16 * L_SEQ * HD;

    gemm_abt<<<dim3(E3 / 64, M_ROWS / 64), 256, 0, stream>>>(
        x, in_w, in_b, qkv, M_ROWS, E3, EMB);
    gemm_abt<<<dim3(EMB / 64, (P_ROWS + 63) / 64), 256, 0, stream>>>(
        pos_emb, pos_w, nullptr, pbuf, P_ROWS, EMB, EMB);
    prep_qkv<<<dim3(L_SEQ / 64, NB * NH), 256, 0, stream>>>(
        qkv, u_bias, v_bias, quB, qvB, kB, vtB);
    prep_p<<<dim3((P_ROWS + 63) / 64), 256, 0, stream>>>(pbuf, pB);
    attn_mfma<<<dim3(512), 256, 0, stream>>>(quB, qvB, kB, vtB, pB, attnb);
    gemm_abt<<<dim3(EMB / 64, M_ROWS / 64), 256, 0, stream>>>(
        attnb, out_w, out_b, out, M_ROWS, EMB, EMB);
}

// Round 3
// 169.887 us; speedup vs baseline: 9.9825x; 1.4397x over previous
//
#include <hip/hip_runtime.h>
#include <math.h>
#include <stdint.h>

// RelPositionMultiheadAttention (Transformer-XL style).
// L=2048, N=4, E=256, H=4, D=64.
//   1) proj_gemm<0>: qkv = x @ in_proj_w.T + b  (fp16 MFMA) -> fused epilogue
//      writes qu=(q*s+u), qv=(q*s+v), K as [bh][i][d] fp16 and V^T [bh][d][j]
//   2) proj_gemm<1>: p = pos_emb @ pos_w.T      (fp16 MFMA) -> pB [h][n][d]
//   3) attn_mfma: fused flash attention, fp16 MFMA, rel-shift via banded BD^T
//   4) proj_gemm<2>: out = attn @ out_proj_w.T + b (fp16 MFMA, fp32 out)

typedef __attribute__((ext_vector_type(8))) _Float16 half8;
typedef __attribute__((ext_vector_type(4))) float f32x4;
typedef unsigned short u16;
typedef unsigned int u32;

namespace {
constexpr int L_SEQ  = 2048;
constexpr int NB     = 4;
constexpr int EMB    = 256;
constexpr int NH     = 4;
constexpr int HD     = 64;
constexpr int E3     = 768;
constexpr int M_ROWS = L_SEQ * NB;     // 8192
constexpr int P_ROWS = 2 * L_SEQ - 1;  // 4095
}

__device__ __forceinline__ u16 f2h(float x) {
    _Float16 h = (_Float16)x;
    return __builtin_bit_cast(u16, h);
}
__device__ __forceinline__ u32 pk2(float a, float b) {
    return (u32)f2h(a) | ((u32)f2h(b) << 16);
}

// ---------------------------------------------------------------------------
// proj_gemm<MODE>: C(M,N) = A(M,256) @ W(N,256)^T (+bias), fp16 MFMA 16x16x32.
// Block: 256 thr = 4 waves; tile 64m x 64n; K=256 in 8 chunks of 32.
// W staged fp32->fp16 in LDS [n][k] with XOR swizzle byte^=(row&7)<<4.
// A rows read per-lane from global (fp32->fp16 for MODE 0/1; fp16 for MODE 2).
// D layout (verified r2): col=lane&15 -> m, row=(lane>>4)*4+reg -> n.
// MODE 0: N=768; n-tile = one {q|k|v} segment x head. Writes quB/qvB/kB
//         [bh][i][64] fp16; V transposed via LDS -> vtB [bh][d][2048] fp16.
// MODE 1: M=4095, N=256 -> pB [h][n][64] fp16.
// MODE 2: A fp16 (attn out), writes fp32 out + bias.
// ---------------------------------------------------------------------------
template <int MODE>
__global__ __launch_bounds__(256, 2) void proj_gemm(
        const void* __restrict__ Ap, const float* __restrict__ W,
        const float* __restrict__ Wb,
        const float* __restrict__ u_bias, const float* __restrict__ v_bias,
        u16* __restrict__ quB, u16* __restrict__ qvB,
        u16* __restrict__ kB,  u16* __restrict__ vtB,
        u16* __restrict__ o16, float* __restrict__ outf) {
    constexpr int NTILES = (MODE == 0) ? 12 : 4;
    __shared__ __align__(16) u16 ws[64 * 256];   // 32 KB, swizzled [n][k]

    const int t    = threadIdx.x;
    const int lane = t & 63;
    const int w    = t >> 6;
    const int il   = lane & 15;
    const int g    = lane >> 4;

    // XCD-chunked bijective swizzle (gridDim %8 == 0 in all modes)
    const int qq = gridDim.x >> 3;
    const int logical = (blockIdx.x & 7) * qq + (blockIdx.x >> 3);
    const int mt = logical / NTILES, nt = logical % NTILES;
    const int m0 = mt * 64, n0 = nt * 64;

    // ---- stage W tile (64 n-rows x 256 k) fp32 -> fp16 LDS, swizzled ----
    {
        const int kc = (t & 31) * 8;   // k offset
        const int rb = t >> 5;         // 0..7
        #pragma unroll
        for (int rr = 0; rr < 8; ++rr) {
            const int row = rb * 8 + rr;
            const float* wr = &W[(size_t)(n0 + row) * 256 + kc];
            float4 f0 = *(const float4*)&wr[0];
            float4 f1 = *(const float4*)&wr[4];
            uint4 pk = make_uint4(pk2(f0.x, f0.y), pk2(f0.z, f0.w),
                                  pk2(f1.x, f1.y), pk2(f1.z, f1.w));
            *(uint4*)((char*)ws + row * 512 + ((kc * 2) ^ ((row & 7) << 4))) = pk;
        }
    }

    // ---- A-row fragments (B-operand): lane's row m, k = c*32 + g*8 ----
    const int m = m0 + w * 16 + il;
    half8 bfrag[8];
    if (MODE == 2) {
        const u16* arow = (const u16*)Ap + (size_t)m * 256;
        #pragma unroll
        for (int c = 0; c < 8; ++c)
            bfrag[c] = *(const half8*)&arow[c * 32 + g * 8];
    } else {
        const int mld = (MODE == 1 && m > P_ROWS - 1) ? (P_ROWS - 1) : m;
        const float* arow = (const float*)Ap + (size_t)mld * 256;
        #pragma unroll
        for (int c = 0; c < 8; ++c) {
            float4 f0 = *(const float4*)&arow[c * 32 + g * 8];
            float4 f1 = *(const float4*)&arow[c * 32 + g * 8 + 4];
            uint4 pk = make_uint4(pk2(f0.x, f0.y), pk2(f0.z, f0.w),
                                  pk2(f1.x, f1.y), pk2(f1.z, f1.w));
            bfrag[c] = __builtin_bit_cast(half8, pk);
        }
    }
    __syncthreads();

    // ---- main loop: 32 MFMAs ----
    f32x4 acc[4] = {};
    __builtin_amdgcn_s_setprio(1);
    #pragma unroll
    for (int c = 0; c < 8; ++c) {
        #pragma unroll
        for (int jt = 0; jt < 4; ++jt) {
            const int row = jt * 16 + il;
            half8 af = *(const half8*)((const char*)ws + row * 512 +
                                       ((c * 64 + g * 16) ^ ((row & 7) << 4)));
            acc[jt] = __builtin_amdgcn_mfma_f32_16x16x32_f16(af, bfrag[c], acc[jt], 0, 0, 0);
        }
    }
    __builtin_amdgcn_s_setprio(0);

    // ---- bias ----
    float av[4][4];
    #pragma unroll
    for (int jt = 0; jt < 4; ++jt)
        #pragma unroll
        for (int r = 0; r < 4; ++r)
            av[jt][r] = acc[jt][r] +
                ((MODE != 1) ? Wb[n0 + jt * 16 + g * 4 + r] : 0.f);

    // ---- epilogues ----
    if (MODE == 0) {
        const int seg = nt >> 2;        // 0=q 1=k 2=v
        const int h   = nt & 3;
        const int i = m >> 2, b = m & 3, bh = b * 4 + h;
        const size_t obase = (((size_t)bh << 11) + i) * 64;
        if (seg == 0) {
            #pragma unroll
            for (int jt = 0; jt < 4; ++jt) {
                const int d0 = jt * 16 + g * 4;
                float uu[4], vv[4];
                #pragma unroll
                for (int r = 0; r < 4; ++r) {
                    uu[r] = av[jt][r] * 0.125f + u_bias[h * 64 + d0 + r];
                    vv[r] = av[jt][r] * 0.125f + v_bias[h * 64 + d0 + r];
                }
                *(uint2*)&quB[obase + d0] = make_uint2(pk2(uu[0], uu[1]), pk2(uu[2], uu[3]));
                *(uint2*)&qvB[obase + d0] = make_uint2(pk2(vv[0], vv[1]), pk2(vv[2], vv[3]));
            }
        } else if (seg == 1) {
            #pragma unroll
            for (int jt = 0; jt < 4; ++jt) {
                const int d0 = jt * 16 + g * 4;
                *(uint2*)&kB[obase + d0] =
                    make_uint2(pk2(av[jt][0], av[jt][1]), pk2(av[jt][2], av[jt][3]));
            }
        } else {
            // V: transpose 64m x 64d through LDS -> vtB [bh][d][j]
            __syncthreads();
            u16* vt = ws;   // reuse, [64 m][68 pitch]
            #pragma unroll
            for (int jt = 0; jt < 4; ++jt) {
                *(uint2*)&vt[(w * 16 + il) * 68 + jt * 16 + g * 4] =
                    make_uint2(pk2(av[jt][0], av[jt][1]), pk2(av[jt][2], av[jt][3]));
            }
            __syncthreads();
            const int d = t & 63, bsel = t >> 6;
            u32 pkx[8];
            #pragma unroll
            for (int p2 = 0; p2 < 8; ++p2)
                pkx[p2] = (u32)vt[(p2 * 8 + bsel) * 68 + d] |
                          ((u32)vt[(p2 * 8 + 4 + bsel) * 68 + d] << 16);
            u16* dst = &vtB[(((size_t)(bsel * 4 + h)) * 64 + d) * 2048 + (m0 >> 2)];
            *(uint4*)&dst[0] = make_uint4(pkx[0], pkx[1], pkx[2], pkx[3]);
            *(uint4*)&dst[8] = make_uint4(pkx[4], pkx[5], pkx[6], pkx[7]);
        }
    } else if (MODE == 1) {
        const int h = nt;
        if (m < P_ROWS) {
            #pragma unroll
            for (int jt = 0; jt < 4; ++jt) {
                const int d0 = jt * 16 + g * 4;
                *(uint2*)&o16[((size_t)h * P_ROWS + m) * 64 + d0] =
                    make_uint2(pk2(av[jt][0], av[jt][1]), pk2(av[jt][2], av[jt][3]));
            }
        }
    } else {
        float* orow = &outf[(size_t)m * 256 + n0];
        #pragma unroll
        for (int jt = 0; jt < 4; ++jt) {
            float4 o = make_float4(av[jt][0], av[jt][1], av[jt][2], av[jt][3]);
            *(float4*)&orow[jt * 16 + g * 4] = o;
        }
    }
}

// ---------------------------------------------------------------------------
// Fused rel-pos flash attention, fp16 MFMA, all-transposed layout.
// grid 512 (XCD-swizzled -> (bh, i0)), block 256 = 4 waves, 64 q-rows/block.
// S^T = mfma(K, Qu); BD^T = mfma(P, Qv) -> banded LDS; Out^T = mfma(V^T, prob).
// D-layout col = q-index everywhere -> lane-uniform softmax state.
// Output written as fp16 [m][e] for the fp16 out-projection.
// ---------------------------------------------------------------------------
__global__ __launch_bounds__(256, 2) void attn_mfma(
        const u16* __restrict__ quB, const u16* __restrict__ qvB,
        const u16* __restrict__ kB,  const u16* __restrict__ vtB,
        const u16* __restrict__ pB,  u16* __restrict__ attn_out) {
    __shared__ __align__(16) u16   k_s[64 * 64];      // [j][d]   8 KB
    __shared__ __align__(16) u16   v_s[64 * 64];      // [d][j]   8 KB
    __shared__ __align__(16) u16   p_s[128 * 64];     // [r][d]  16 KB
    __shared__ __align__(16) float bd_s[4][16 * 84];  // per-wave [il][rr] 21 KB
    __shared__ __align__(16) u16   prob_s[4][16 * 64];// per-wave [il][j]  8 KB

    const int t    = threadIdx.x;
    const int lane = t & 63;
    const int w    = t >> 6;
    const int il   = lane & 15;
    const int g    = lane >> 4;

    const int logical = ((blockIdx.x & 7) << 6) + (blockIdx.x >> 3);
    const int bh = logical >> 5;
    const int i0 = (logical & 31) * 64;
    const int b  = bh >> 2, h = bh & 3;

    half8 qu_f[2], qv_f[2];
    {
        const size_t qrow = ((size_t)bh * L_SEQ + i0 + w * 16 + il) * HD;
        qu_f[0] = *(const half8*)&quB[qrow + g * 8];
        qu_f[1] = *(const half8*)&quB[qrow + 32 + g * 8];
        qv_f[0] = *(const half8*)&qvB[qrow + g * 8];
        qv_f[1] = *(const half8*)&qvB[qrow + 32 + g * 8];
    }

    const int r0w = 48 - 16 * w;
    int krd[4][2], prd[5][2], pbrd[2], pwr[4];
    #pragma unroll
    for (int x4 = 0; x4 < 4; ++x4)
        #pragma unroll
        for (int c = 0; c < 2; ++c) {
            int row = x4 * 16 + il;
            krd[x4][c] = row * 128 + ((c * 64 + g * 16) ^ ((row & 7) << 4));
        }
    #pragma unroll
    for (int rt = 0; rt < 5; ++rt)
        #pragma unroll
        for (int c = 0; c < 2; ++c) {
            int row = r0w + rt * 16 + il;
            prd[rt][c] = row * 128 + ((c * 64 + g * 16) ^ ((row & 7) << 4));
        }
    #pragma unroll
    for (int c = 0; c < 2; ++c)
        pbrd[c] = il * 128 + ((c * 64 + g * 16) ^ ((il & 7) << 4));
    #pragma unroll
    for (int jt = 0; jt < 4; ++jt)
        pwr[jt] = il * 128 + (((jt * 16 + g * 4) * 2) ^ ((il & 7) << 4));
    const int bdwr = il * 84 + g * 4;
    const int bdrd = il * 83 + 15 + g * 4;

    f32x4 outacc[4] = {};
    float m_run = -INFINITY, l_run = 0.f;

    for (int kt = 0; kt < 32; ++kt) {
        const int j0 = kt * 64;
        const int nbase = 1984 - i0 + j0;
        __syncthreads();
        {
            const int rw = t >> 3;
            const int a  = t & 7;
            #pragma unroll
            for (int kr = 0; kr < 2; ++kr) {
                const int j = kr * 32 + rw;
                uint4 val = *(const uint4*)&kB[((size_t)bh * L_SEQ + j0 + j) * HD + a * 8];
                *(uint4*)((char*)k_s + (j * 128 + ((a * 16) ^ ((j & 7) << 4)))) = val;
            }
            #pragma unroll
            for (int vr = 0; vr < 2; ++vr) {
                const int d = vr * 32 + rw;
                uint4 val = *(const uint4*)&vtB[((size_t)bh * HD + d) * L_SEQ + j0 + a * 8];
                *(uint4*)((char*)v_s + (d * 128 + ((a * 16) ^ ((d & 7) << 4)))) = val;
            }
            #pragma unroll
            for (int pr = 0; pr < 4; ++pr) {
                const int r = pr * 32 + rw;
                int n = nbase + r; n = n > (P_ROWS - 1) ? (P_ROWS - 1) : n;
                uint4 val = *(const uint4*)&pB[((size_t)h * P_ROWS + n) * HD + a * 8];
                *(uint4*)((char*)p_s + (r * 128 + ((a * 16) ^ ((r & 7) << 4)))) = val;
            }
        }
        __syncthreads();

        // ---- BD^T band ----
        __builtin_amdgcn_s_setprio(1);
        #pragma unroll
        for (int rt = 0; rt < 5; ++rt) {
            f32x4 acc = {};
            #pragma unroll
            for (int c = 0; c < 2; ++c) {
                half8 a = *(const half8*)((const char*)p_s + prd[rt][c]);
                acc = __builtin_amdgcn_mfma_f32_16x16x32_f16(a, qv_f[c], acc, 0, 0, 0);
            }
            *(f32x4*)&bd_s[w][bdwr + rt * 16] = acc;
        }
        __builtin_amdgcn_s_setprio(0);

        // ---- AC (S^T) + rel-shift combine ----
        float sreg[16];
        __builtin_amdgcn_s_setprio(1);
        #pragma unroll
        for (int jt = 0; jt < 4; ++jt) {
            f32x4 acc = {};
            #pragma unroll
            for (int c = 0; c < 2; ++c) {
                half8 a = *(const half8*)((const char*)k_s + krd[jt][c]);
                acc = __builtin_amdgcn_mfma_f32_16x16x32_f16(a, qu_f[c], acc, 0, 0, 0);
            }
            #pragma unroll
            for (int tt = 0; tt < 4; ++tt)
                sreg[jt * 4 + tt] = acc[tt] + bd_s[w][bdrd + jt * 16 + tt];
        }
        __builtin_amdgcn_s_setprio(0);

        // ---- online softmax ----
        float mx = sreg[0];
        #pragma unroll
        for (int z = 1; z < 16; ++z) mx = fmaxf(mx, sreg[z]);
        mx = fmaxf(mx, __shfl_xor(mx, 16));
        mx = fmaxf(mx, __shfl_xor(mx, 32));
        const float m_new = fmaxf(m_run, mx);
        const float corr = __expf(m_run - m_new);
        float lsum = 0.f;
        #pragma unroll
        for (int z = 0; z < 16; ++z) { sreg[z] = __expf(sreg[z] - m_new); lsum += sreg[z]; }
        lsum += __shfl_xor(lsum, 16);
        lsum += __shfl_xor(lsum, 32);
        l_run = l_run * corr + lsum;
        m_run = m_new;
        #pragma unroll
        for (int dt = 0; dt < 4; ++dt) outacc[dt] *= corr;

        // ---- pack probabilities ----
        #pragma unroll
        for (int jt = 0; jt < 4; ++jt) {
            u32 lo = pk2(sreg[jt * 4 + 0], sreg[jt * 4 + 1]);
            u32 hi = pk2(sreg[jt * 4 + 2], sreg[jt * 4 + 3]);
            *(uint2*)((char*)&prob_s[w][0] + pwr[jt]) = make_uint2(lo, hi);
        }

        // ---- PV ----
        half8 pfrag[2];
        #pragma unroll
        for (int c = 0; c < 2; ++c)
            pfrag[c] = *(const half8*)((const char*)&prob_s[w][0] + pbrd[c]);
        __builtin_amdgcn_s_setprio(1);
        #pragma unroll
        for (int dt = 0; dt < 4; ++dt) {
            #pragma unroll
            for (int c = 0; c < 2; ++c) {
                half8 a = *(const half8*)((const char*)v_s + krd[dt][c]);
                outacc[dt] = __builtin_amdgcn_mfma_f32_16x16x32_f16(a, pfrag[c], outacc[dt], 0, 0, 0);
            }
        }
        __builtin_amdgcn_s_setprio(0);
    }

    // ---- epilogue: fp16 [m][e] ----
    const float inv = 1.f / l_run;
    const int m = (i0 + w * 16 + il) * NB + b;
    u16* orow = &attn_out[(size_t)m * EMB + h * HD];
    #pragma unroll
    for (int dt = 0; dt < 4; ++dt) {
        u32 lo = pk2(outacc[dt][0] * inv, outacc[dt][1] * inv);
        u32 hi = pk2(outacc[dt][2] * inv, outacc[dt][3] * inv);
        *(uint2*)&orow[dt * 16 + g * 4] = make_uint2(lo, hi);
    }
}

// ---------------------------------------------------------------------------
extern "C" void kernel_launch(void* const* d_in, const int* in_sizes, int n_in,
                              void* d_out, int out_size, void* d_ws, size_t ws_size,
                              hipStream_t stream) {
    const float* x        = (const float*)d_in[0];
    const float* pos_emb  = (const float*)d_in[1];
    const float* in_w     = (const float*)d_in[2];
    const float* in_b     = (const float*)d_in[3];
    const float* pos_w    = (const float*)d_in[4];
    const float* u_bias   = (const float*)d_in[5];
    const float* v_bias   = (const float*)d_in[6];
    const float* out_w    = (const float*)d_in[7];
    const float* out_b    = (const float*)d_in[8];
    float* out = (float*)d_out;

    // fp16 workspace (~23 MB)
    u16* quB   = (u16*)d_ws;
    u16* qvB   = quB + (size_t)16 * L_SEQ * HD;
    u16* kB    = qvB + (size_t)16 * L_SEQ * HD;
    u16* vtB   = kB  + (size_t)16 * L_SEQ * HD;
    u16* pB    = vtB + (size_t)16 * L_SEQ * HD;
    u16* attnb = pB  + (size_t)NH * P_ROWS * HD;

    proj_gemm<0><<<dim3(128 * 12), 256, 0, stream>>>(
        x, in_w, in_b, u_bias, v_bias, quB, qvB, kB, vtB, nullptr, nullptr);
    proj_gemm<1><<<dim3(64 * 4), 256, 0, stream>>>(
        pos_emb, pos_w, nullptr, nullptr, nullptr,
        nullptr, nullptr, nullptr, nullptr, pB, nullptr);
    attn_mfma<<<dim3(512), 256, 0, stream>>>(quB, qvB, kB, vtB, pB, attnb);
    proj_gemm<2><<<dim3(128 * 4), 256, 0, stream>>>(
        attnb, out_w, out_b, nullptr, nullptr,
        nullptr, nullptr, nullptr, nullptr, nullptr, out);
}